// Round 6
// baseline (153.625 us; speedup 1.0000x reference)
//
#include <hip/hip_runtime.h>
#include <hip/hip_bf16.h>
#include <math.h>

#define NS 4096          // samples per view
#define NI 8192          // total instances (2 views)
#define DIM 512
#define TEMP_INV 2.0f    // 1/t, t = 0.5
#define TILE 256         // output tile side
#define NBLK 32          // NI/TILE tile blocks per side
#define NTRI (NBLK * (NBLK + 1) / 2)   // 528 upper-triangle tiles
#define BK 64            // k-elems staged per step
#define NSTG (DIM / BK)  // 8 stages

typedef short v8s __attribute__((ext_vector_type(8)));   // 8 bf16 (4 VGPRs)
typedef float v4f __attribute__((ext_vector_type(4)));   // 4 fp32 acc

// async global->LDS, 16B per lane. LDS dest is wave-uniform base + lane*16.
__device__ __forceinline__ void gld16(const void* g, void* l) {
    __builtin_amdgcn_global_load_lds(
        (const __attribute__((address_space(1))) void*)g,
        (__attribute__((address_space(3))) void*)l, 16, 0, 0);
}

// ---------------------------------------------------------------------------
// Kernel 1: norms + positive dots (fp32), cast X -> bf16; also zeros rowsum.
// ---------------------------------------------------------------------------
__global__ __launch_bounds__(256) void prep_kernel(
        const float* __restrict__ x1, const float* __restrict__ x2,
        __hip_bfloat16* __restrict__ Xb, float* __restrict__ rnorm,
        float* __restrict__ posdot, float* __restrict__ rowsum) {
    const int t = threadIdx.x;
    if (t < 4) rowsum[blockIdx.x * 4 + t] = 0.f;   // 2048 blocks x 4 = NI
    const int sub = t >> 7;
    const int c4 = t & 127;
    const int i = blockIdx.x * 2 + sub;
    const float4 a = ((const float4*)(x1 + (size_t)i * DIM))[c4];
    const float4 b = ((const float4*)(x2 + (size_t)i * DIM))[c4];
    float s1 = a.x*a.x + a.y*a.y + a.z*a.z + a.w*a.w;
    float s2 = b.x*b.x + b.y*b.y + b.z*b.z + b.w*b.w;
    float dd = a.x*b.x + a.y*b.y + a.z*b.z + a.w*b.w;

    auto bfbits = [](float v) -> unsigned short {
        __hip_bfloat16 h = __float2bfloat16(v);
        return *(unsigned short*)&h;
    };
    ushort4 pa = { bfbits(a.x), bfbits(a.y), bfbits(a.z), bfbits(a.w) };
    ushort4 pb = { bfbits(b.x), bfbits(b.y), bfbits(b.z), bfbits(b.w) };
    ((ushort4*)(Xb + (size_t)i * DIM))[c4] = pa;
    ((ushort4*)(Xb + (size_t)(i + NS) * DIM))[c4] = pb;

    #pragma unroll
    for (int off = 32; off; off >>= 1) {
        s1 += __shfl_down(s1, off, 64);
        s2 += __shfl_down(s2, off, 64);
        dd += __shfl_down(dd, off, 64);
    }
    __shared__ float red[2][2][3];
    if ((t & 63) == 0) {
        const int w = (t >> 6) & 1;
        red[sub][w][0] = s1; red[sub][w][1] = s2; red[sub][w][2] = dd;
    }
    __syncthreads();
    if ((t & 127) == 0) {
        s1 = red[sub][0][0] + red[sub][1][0];
        s2 = red[sub][0][1] + red[sub][1][1];
        dd = red[sub][0][2] + red[sub][1][2];
        rnorm[i]      = 1.0f / sqrtf(s1);
        rnorm[i + NS] = 1.0f / sqrtf(s2);
        posdot[i] = dd;
    }
}

// ---------------------------------------------------------------------------
// One 8-phase sub-phase (4 per K-tile). H = ta-half (0: ta0-3, 1: ta4-7),
// K = ksub (k 0-31 / 32-63). STAGE: 0 none, 1 = row-quads 0,1, 2 = quads 2,3
// of next tile (front-loaded so the tile-end vmcnt(0) waits on >=2-phase-old
// loads). Structure per m201 template: reads -> stage -> barrier ->
// lgkmcnt(0) -> setprio(1) -> 16 indep MFMA -> setprio(0) -> [vmcnt(0) at
// tile end] -> barrier. Counted-wait discipline: loads stay in flight
// across the 6 intermediate barriers of a tile (T3+T4); setprio = T5.
// ---------------------------------------------------------------------------
template<int H, int K, int STAGE>
__device__ __forceinline__ void phase(
        const char* tA, const char* tB, int aoff, int boff,
        v4f (&acc)[8][4], const short* X, int gA, int gB, int k0,
        short* dst, int lbs, bool st, bool last) {
    v8s a_[4], b_[4];
    #pragma unroll
    for (int i = 0; i < 4; ++i)
        a_[i] = *(const v8s*)(tA + ((aoff + (H * 4 + i) * 2048) ^ (K * 64)));
    #pragma unroll
    for (int j = 0; j < 4; ++j)
        b_[j] = *(const v8s*)(tB + ((boff + j * 2048) ^ (K * 64)));
    if (STAGE == 1 && st) {
        gld16(X + gA + k0,         dst + lbs);
        gld16(X + gA + k0 + 32768, dst + lbs + 4096);
        gld16(X + gB + k0,         dst + 16384 + lbs);
        gld16(X + gB + k0 + 32768, dst + 16384 + lbs + 4096);
    }
    if (STAGE == 2 && st) {
        gld16(X + gA + k0 + 65536, dst + lbs + 8192);
        gld16(X + gA + k0 + 98304, dst + lbs + 12288);
        gld16(X + gB + k0 + 65536, dst + 16384 + lbs + 8192);
        gld16(X + gB + k0 + 98304, dst + 16384 + lbs + 12288);
    }
    __builtin_amdgcn_s_barrier();
    asm volatile("s_waitcnt lgkmcnt(0)");
    __builtin_amdgcn_s_setprio(1);
    #pragma unroll
    for (int i = 0; i < 4; ++i)
        #pragma unroll
        for (int j = 0; j < 4; ++j)
            acc[H * 4 + i][j] = __builtin_amdgcn_mfma_f32_16x16x32_bf16(
                a_[i], b_[j], acc[H * 4 + i][j], 0, 0, 0);
    __builtin_amdgcn_s_setprio(0);
    if (last) asm volatile("s_waitcnt vmcnt(0)");
    __builtin_amdgcn_s_barrier();
}

// ---------------------------------------------------------------------------
// Kernel 2: upper-triangle 256x256 tiles of G = Xb*Xb^T, 8-phase schedule.
// 512 thr / 8 waves (2x4), wave tile 128x64, acc[8][4]=128 regs, BK=64
// double-buffered (128 KB, 1 block/CU). Rounds 3/5 measured this geometry
// AT the 2-phase structural ceiling (421 TF wall-rate = 612 TF steady =
// m233's 607); the 8-phase split is the documented 2.5x lever (m196/m218/
// m201). Addressing/swizzle/epilogue identical to round 5 (0 bank
// conflicts, absmax 3e-8). Accumulation order per acc element unchanged.
// ---------------------------------------------------------------------------
__global__ __launch_bounds__(512, 2) void sim_kernel(
        const __hip_bfloat16* __restrict__ Xbh, const float* __restrict__ rnorm,
        float* __restrict__ rowsum, float* __restrict__ negpart) {
    // --- XCD-aware bijective swizzle: 528 = 8 * 66 exactly
    const int raw = blockIdx.x;
    const int id = (raw & 7) * 66 + (raw >> 3);
    // --- triangular decode: id -> (bi, bj), bi<=bj, NBLK=32
    int bi = (int)((65.0f - sqrtf(4225.0f - 8.0f * (float)id)) * 0.5f);
    int base = bi * (65 - bi) / 2;
    if (id < base)                       { --bi; base = bi * (65 - bi) / 2; }
    else if (id >= base + (NBLK - bi))   { ++bi; base = bi * (65 - bi) / 2; }
    const int bj = bi + (id - base);
    const bool offdiag = (bj != bi);
    const int i0 = bi * TILE, j0 = bj * TILE;

    __shared__ __align__(16) short lds[2][2][TILE * BK];   // [buf][A/B], 128 KB
    __shared__ float sRow[4][TILE];            // [wc][row]   4 KB
    __shared__ float sCol[2][TILE];            // [wr][col]   2 KB
    __shared__ float sNeg[8];

    const int t = threadIdx.x;                 // 0..511
    const int lane = t & 63, wv = t >> 6;      // 8 waves
    const int wr = wv >> 2, wc = wv & 3;       // 2 x 4 wave grid
    const int r16 = lane & 15, quad = lane >> 4;

    const short* X = reinterpret_cast<const short*>(Xbh);

    // --- staging bases (q-independent; q strides are immediates)
    const int grow = t >> 3;                           // 0..63
    const int kc   = (t & 7) ^ (grow & 7);
    const int gA   = (i0 + grow) * DIM + kc * 8;       // short index
    const int gB   = (j0 + grow) * DIM + kc * 8;
    const int lbs  = wv * 512;                         // short index in tile

    // --- fragment read bases (bytes within a 32 KB tile; ta/tb add 2048)
    const int slot = (quad ^ (r16 & 7)) * 16;
    const int aoff = (wr * 128 + r16) * 128 + slot;
    const int boff = (wc * 64  + r16) * 128 + slot;

    v4f acc[8][4];
    #pragma unroll
    for (int a = 0; a < 8; ++a)
        #pragma unroll
        for (int b = 0; b < 4; ++b)
            acc[a][b] = (v4f){0.f, 0.f, 0.f, 0.f};

    // --- prologue: stage first K-tile into buf0, full drain once
    #pragma unroll
    for (int q = 0; q < 4; ++q) {
        gld16(X + gA + q * 32768, &lds[0][0][lbs + q * 4096]);
        gld16(X + gB + q * 32768, &lds[0][1][lbs + q * 4096]);
    }
    asm volatile("s_waitcnt vmcnt(0)");
    __builtin_amdgcn_s_barrier();

    const char* ldsb = (const char*)&lds[0][0][0];

    // --- main loop: 8 K-tiles x 4 phases
    for (int s = 0; s < NSTG; ++s) {
        const int cur = s & 1;
        const char* tA = ldsb + cur * 65536;   // A tile base
        const char* tB = tA + 32768;           // B tile base
        short* dst = &lds[1 - cur][0][0];
        const int k0 = (s + 1) * BK;
        const bool st = (s + 1 < NSTG);
        phase<0, 0, 1>(tA, tB, aoff, boff, acc, X, gA, gB, k0, dst, lbs, st, false);
        phase<0, 1, 2>(tA, tB, aoff, boff, acc, X, gA, gB, k0, dst, lbs, st, false);
        phase<1, 0, 0>(tA, tB, aoff, boff, acc, X, gA, gB, k0, dst, lbs, st, false);
        phase<1, 1, 0>(tA, tB, aoff, boff, acc, X, gA, gB, k0, dst, lbs, st, true);
    }

    // --- epilogue: sim2 = 2*D*r_i*r_j; masked (j==i, j==i^NS) -> exp contributes 1
    float rc[4];
    int colg[4];
    #pragma unroll
    for (int tb = 0; tb < 4; ++tb) {
        colg[tb] = j0 + wc * 64 + tb * 16 + r16;
        rc[tb] = rnorm[colg[tb]];
    }
    float negacc = 0.f;
    float colacc[4] = {0.f, 0.f, 0.f, 0.f};
    #pragma unroll
    for (int ta = 0; ta < 8; ++ta) {
        #pragma unroll
        for (int r = 0; r < 4; ++r) {
            const int rowl = wr * 128 + ta * 16 + quad * 4 + r;
            const int rowg = i0 + rowl;
            const float rr = rnorm[rowg] * TEMP_INV;
            float rowe = 0.f;
            #pragma unroll
            for (int tb = 0; tb < 4; ++tb) {
                const float sim2 = acc[ta][tb][r] * rr * rc[tb];
                const bool masked = (colg[tb] == rowg) || (colg[tb] == (rowg ^ NS));
                const float e = masked ? 1.0f : __expf(sim2);
                rowe   += e;
                negacc += masked ? 0.0f : sim2;
                colacc[tb] += e;
            }
            #pragma unroll
            for (int off = 1; off < 16; off <<= 1)
                rowe += __shfl_xor(rowe, off, 64);
            if (r16 == 0) sRow[wc][rowl] = rowe;
        }
    }
    #pragma unroll
    for (int tb = 0; tb < 4; ++tb) {
        colacc[tb] += __shfl_xor(colacc[tb], 16, 64);
        colacc[tb] += __shfl_xor(colacc[tb], 32, 64);
        if (quad == 0) sCol[wr][wc * 64 + tb * 16 + r16] = colacc[tb];
    }
    if (offdiag) negacc *= 2.0f;
    #pragma unroll
    for (int off = 1; off < 64; off <<= 1)
        negacc += __shfl_xor(negacc, off, 64);
    if (lane == 0) sNeg[wv] = negacc;

    __syncthreads();

    if (t < TILE) {
        atomicAdd(&rowsum[i0 + t],
                  sRow[0][t] + sRow[1][t] + sRow[2][t] + sRow[3][t]);
    } else if (offdiag) {
        const int c = t - TILE;
        atomicAdd(&rowsum[j0 + c], sCol[0][c] + sCol[1][c]);
    }
    if (t == 0) {
        float n = 0.f;
        #pragma unroll
        for (int w = 0; w < 8; ++w) n += sNeg[w];
        negpart[id] = n;
    }
}

// ---------------------------------------------------------------------------
// Kernel 3: final scalars. E_i = rowsum[i] (includes +2 from masked entries).
// ---------------------------------------------------------------------------
__global__ __launch_bounds__(1024) void final_kernel(
        const float* __restrict__ rowsum, const float* __restrict__ rnorm,
        const float* __restrict__ posdot, const float* __restrict__ negpart,
        float* __restrict__ out) {
    const int t = threadIdx.x;
    float lsum = 0.f, psum = 0.f, nsum = 0.f;
    #pragma unroll
    for (int i = t; i < NI; i += 1024) {
        const int s = i & (NS - 1);
        const float sp = posdot[s] * rnorm[i] * rnorm[i ^ NS] * TEMP_INV;
        const float E = rowsum[i];
        lsum += logf(expf(sp) + E) - sp;
        psum += sp;
    }
    if (t < NTRI)
        nsum = negpart[t];
    __shared__ float red[3][16];
    #pragma unroll
    for (int off = 32; off; off >>= 1) {
        lsum += __shfl_down(lsum, off, 64);
        psum += __shfl_down(psum, off, 64);
        nsum += __shfl_down(nsum, off, 64);
    }
    if ((t & 63) == 0) {
        red[0][t >> 6] = lsum; red[1][t >> 6] = psum; red[2][t >> 6] = nsum;
    }
    __syncthreads();
    if (t == 0) {
        lsum = 0.f; psum = 0.f; nsum = 0.f;
        #pragma unroll
        for (int w = 0; w < 16; ++w) {
            lsum += red[0][w]; psum += red[1][w]; nsum += red[2][w];
        }
        out[0] = lsum / (float)NI;
        out[1] = psum / (float)NI;
        out[2] = nsum / ((float)NI * (float)(NI - 2));
    }
}

// ---------------------------------------------------------------------------
extern "C" void kernel_launch(void* const* d_in, const int* in_sizes, int n_in,
                              void* d_out, int out_size, void* d_ws, size_t ws_size,
                              hipStream_t stream) {
    const float* x1 = (const float*)d_in[0];
    const float* x2 = (const float*)d_in[1];
    float* out = (float*)d_out;

    char* ws = (char*)d_ws;
    __hip_bfloat16* Xb = (__hip_bfloat16*)ws;                 // NI*DIM*2 = 8 MB
    float* rnorm  = (float*)(ws + (size_t)NI * DIM * 2);      // NI
    float* posdot = rnorm + NI;                               // NS
    float* rowsum = posdot + NS;                              // NI (zeroed in prep)
    float* negpart = rowsum + NI;                             // NTRI (all written)

    prep_kernel<<<NS / 2, 256, 0, stream>>>(x1, x2, Xb, rnorm, posdot, rowsum);

    sim_kernel<<<NTRI, 512, 0, stream>>>(Xb, rnorm, rowsum, negpart);

    final_kernel<<<1, 1024, 0, stream>>>(rowsum, rnorm, posdot, negpart, out);
}

// Round 7
// 119.127 us; speedup vs baseline: 1.2896x; 1.2896x over previous
//
#include <hip/hip_runtime.h>
#include <hip/hip_bf16.h>
#include <math.h>

#define NS 4096          // samples per view
#define NI 8192          // total instances (2 views)
#define DIM 512
#define TEMP_INV 2.0f    // 1/t, t = 0.5
#define TILE 128         // output tile side
#define NBLK 64          // NI/TILE tile blocks per side
#define NTRI (NBLK * (NBLK + 1) / 2)   // 2080 upper-triangle tiles
#define BK 64            // k-elems staged per step
#define NSTG (DIM / BK)  // 8 stages

typedef short v8s __attribute__((ext_vector_type(8)));   // 8 bf16 (4 VGPRs)
typedef float v4f __attribute__((ext_vector_type(4)));   // 4 fp32 acc

// async global->LDS, 16B per lane. LDS dest is wave-uniform base + lane*16.
__device__ __forceinline__ void gld16(const void* g, void* l) {
    __builtin_amdgcn_global_load_lds(
        (const __attribute__((address_space(1))) void*)g,
        (__attribute__((address_space(3))) void*)l, 16, 0, 0);
}

// ---------------------------------------------------------------------------
// Kernel 1: norms + positive dots (fp32), cast X -> bf16; also zeros rowsum.
// ---------------------------------------------------------------------------
__global__ __launch_bounds__(256) void prep_kernel(
        const float* __restrict__ x1, const float* __restrict__ x2,
        __hip_bfloat16* __restrict__ Xb, float* __restrict__ rnorm,
        float* __restrict__ posdot, float* __restrict__ rowsum) {
    const int t = threadIdx.x;
    if (t < 4) rowsum[blockIdx.x * 4 + t] = 0.f;   // 2048 blocks x 4 = NI
    const int sub = t >> 7;
    const int c4 = t & 127;
    const int i = blockIdx.x * 2 + sub;
    const float4 a = ((const float4*)(x1 + (size_t)i * DIM))[c4];
    const float4 b = ((const float4*)(x2 + (size_t)i * DIM))[c4];
    float s1 = a.x*a.x + a.y*a.y + a.z*a.z + a.w*a.w;
    float s2 = b.x*b.x + b.y*b.y + b.z*b.z + b.w*b.w;
    float dd = a.x*b.x + a.y*b.y + a.z*b.z + a.w*b.w;

    auto bfbits = [](float v) -> unsigned short {
        __hip_bfloat16 h = __float2bfloat16(v);
        return *(unsigned short*)&h;
    };
    ushort4 pa = { bfbits(a.x), bfbits(a.y), bfbits(a.z), bfbits(a.w) };
    ushort4 pb = { bfbits(b.x), bfbits(b.y), bfbits(b.z), bfbits(b.w) };
    ((ushort4*)(Xb + (size_t)i * DIM))[c4] = pa;
    ((ushort4*)(Xb + (size_t)(i + NS) * DIM))[c4] = pb;

    #pragma unroll
    for (int off = 32; off; off >>= 1) {
        s1 += __shfl_down(s1, off, 64);
        s2 += __shfl_down(s2, off, 64);
        dd += __shfl_down(dd, off, 64);
    }
    __shared__ float red[2][2][3];
    if ((t & 63) == 0) {
        const int w = (t >> 6) & 1;
        red[sub][w][0] = s1; red[sub][w][1] = s2; red[sub][w][2] = dd;
    }
    __syncthreads();
    if ((t & 127) == 0) {
        s1 = red[sub][0][0] + red[sub][1][0];
        s2 = red[sub][0][1] + red[sub][1][1];
        dd = red[sub][0][2] + red[sub][1][2];
        rnorm[i]      = 1.0f / sqrtf(s1);
        rnorm[i + NS] = 1.0f / sqrtf(s2);
        posdot[i] = dd;
    }
}

// ---------------------------------------------------------------------------
// Kernel 2: upper-triangle 128x128 tiles of G = Xb*Xb^T — m97 structure.
// 256 thr / 4 waves (2x2), wave tile 64x64 -> acc[4][4] = 64 regs.
// SINGLE 32 KB LDS buffer, 2 barriers per K-step:
//     barrier (prior reads done) -> stage 8x gld16 -> barrier (compiler
//     drains vmcnt -> staged visible) -> ds_read frags -> 32 MFMA.
// Rationale: rounds 5/6 proved the 256x256 1-block/CU configs sit at the
// lockstep-serialization ceiling (~600 TF steady) regardless of phase
// schedule — barriers force all waves into read-bursts then MFMA-bursts, so
// LDS and matrix pipes alternate instead of overlapping. The proven escape
// is INTER-block overlap (m114/m97: 874-912 TF at 128^2 with ~3 blocks/CU).
// Round 0 got only 487 TF because double-buffering (68 KB) capped residency
// at 2 blocks/CU. This kernel: 32 KB + 2.1 KB epilogue -> 3-4 blocks/CU.
// Addressing fully folded to immediates (round-5 technique) so total regs
// ~= 64 acc + ~50 arch; __launch_bounds__(256,3) caps ~170 (no spill;
// tripwire: WRITE_SIZE > 10 MB = spill = void round).
// LDS layout: row stride 128 B = 8 x 16B chunks, slot cs = kc ^ (row&7)
// (round-0 layout, measured 0 bank conflicts; 2-way aliasing = free).
// ---------------------------------------------------------------------------
__global__ __launch_bounds__(256, 3) void sim_kernel(
        const __hip_bfloat16* __restrict__ Xbh, const float* __restrict__ rnorm,
        float* __restrict__ rowsum, float* __restrict__ negpart) {
    // --- XCD-aware bijective swizzle: 2080 = 8 * 260 exactly
    const int raw = blockIdx.x;
    const int id = (raw & 7) * 260 + (raw >> 3);
    // --- triangular decode: id -> (bi, bj), bi<=bj (round-0 proven, NBLK=64)
    int bi = (int)((129.0f - sqrtf(16641.0f - 8.0f * (float)id)) * 0.5f);
    int base = bi * (129 - bi) / 2;
    if (id < base)                     { --bi; base = bi * (129 - bi) / 2; }
    else if (id >= base + (64 - bi))   { ++bi; base = bi * (129 - bi) / 2; }
    const int bj = bi + (id - base);
    const bool offdiag = (bj != bi);
    const int i0 = bi * TILE, j0 = bj * TILE;

    __shared__ __align__(16) short lds[2][TILE * BK];  // [A/B], 32 KB total
    __shared__ float sRow[2][TILE];            // [wc][row]
    __shared__ float sCol[2][TILE];            // [wr][col]
    __shared__ float sNeg[4];

    const int t = threadIdx.x;                 // 0..255
    const int lane = t & 63, wv = t >> 6;      // 4 waves
    const int wr = wv >> 1, wc = wv & 1;       // 2x2 wave grid, 64x64 each
    const int r16 = lane & 15, quad = lane >> 4;

    const short* X = reinterpret_cast<const short*>(Xbh);

    // --- staging bases (q-independent; q strides are immediates).
    // instr q covers chunks lin = q*256 + t: row = q*32 + (t>>3),
    // slot cs = t&7 holds global k-chunk kc = cs ^ (row&7) (q*32 preserves
    // row&7). Global: q adds 32 rows = 16384 shorts; LDS: q adds 2048 shorts.
    const int grow = t >> 3;                           // 0..31
    const int kc   = (t & 7) ^ (grow & 7);
    const int gA   = (i0 + grow) * DIM + kc * 8;       // short index
    const int gB   = (j0 + grow) * DIM + kc * 8;
    const int lbs  = wv * 512;                         // shorts; +q*2048

    // --- fragment read bases (bytes; tt adds 2048, s2 is ^64, B at +16384).
    // row&7 == r16&7 (wr*64, tt*16 are 0 mod 8), so slot is tt-independent.
    const int slot = (quad ^ (r16 & 7)) * 16;
    const int aoff = (wr * 64 + r16) * 128 + slot;
    const int boff = (wc * 64 + r16) * 128 + slot;

    v4f acc[4][4];
    #pragma unroll
    for (int a = 0; a < 4; ++a)
        #pragma unroll
        for (int b = 0; b < 4; ++b)
            acc[a][b] = (v4f){0.f, 0.f, 0.f, 0.f};

    const char* ldsb = (const char*)&lds[0][0];

    // --- main loop: 8 K-steps of BK=64, single-buffered (m97 2-barrier)
    for (int s = 0; s < NSTG; ++s) {
        const int k0 = s * BK;
        __syncthreads();                       // prior iter's reads complete
        #pragma unroll
        for (int q = 0; q < 4; ++q) {
            gld16(X + gA + k0 + q * 16384, &lds[0][lbs + q * 2048]);
            gld16(X + gB + k0 + q * 16384, &lds[1][lbs + q * 2048]);
        }
        __syncthreads();                       // vmcnt drained -> tile ready
        #pragma unroll
        for (int s2 = 0; s2 < 2; ++s2) {
            v8s af[4], bf[4];
            #pragma unroll
            for (int tt = 0; tt < 4; ++tt) {
                af[tt] = *(const v8s*)(ldsb + ((aoff + tt * 2048) ^ (s2 * 64)));
                bf[tt] = *(const v8s*)(ldsb + 16384 + ((boff + tt * 2048) ^ (s2 * 64)));
            }
            #pragma unroll
            for (int ta = 0; ta < 4; ++ta)
                #pragma unroll
                for (int tb = 0; tb < 4; ++tb)
                    acc[ta][tb] = __builtin_amdgcn_mfma_f32_16x16x32_bf16(
                        af[ta], bf[tb], acc[ta][tb], 0, 0, 0);
        }
    }

    // --- epilogue: sim2 = 2*D*r_i*r_j; masked (j==i, j==i^NS) -> exp contributes 1
    float rc[4];
    int colg[4];
    #pragma unroll
    for (int tb = 0; tb < 4; ++tb) {
        colg[tb] = j0 + wc * 64 + tb * 16 + r16;
        rc[tb] = rnorm[colg[tb]];
    }
    float negacc = 0.f;
    float colacc[4] = {0.f, 0.f, 0.f, 0.f};
    #pragma unroll
    for (int ta = 0; ta < 4; ++ta) {
        #pragma unroll
        for (int r = 0; r < 4; ++r) {
            const int rowl = wr * 64 + ta * 16 + quad * 4 + r;
            const int rowg = i0 + rowl;
            const float rr = rnorm[rowg] * TEMP_INV;
            float rowe = 0.f;
            #pragma unroll
            for (int tb = 0; tb < 4; ++tb) {
                const float sim2 = acc[ta][tb][r] * rr * rc[tb];
                const bool masked = (colg[tb] == rowg) || (colg[tb] == (rowg ^ NS));
                const float e = masked ? 1.0f : __expf(sim2);
                rowe   += e;
                negacc += masked ? 0.0f : sim2;
                colacc[tb] += e;
            }
            #pragma unroll
            for (int off = 1; off < 16; off <<= 1)
                rowe += __shfl_xor(rowe, off, 64);
            if (r16 == 0) sRow[wc][rowl] = rowe;
        }
    }
    #pragma unroll
    for (int tb = 0; tb < 4; ++tb) {
        colacc[tb] += __shfl_xor(colacc[tb], 16, 64);
        colacc[tb] += __shfl_xor(colacc[tb], 32, 64);
        if (quad == 0) sCol[wr][wc * 64 + tb * 16 + r16] = colacc[tb];
    }
    if (offdiag) negacc *= 2.0f;
    #pragma unroll
    for (int off = 1; off < 64; off <<= 1)
        negacc += __shfl_xor(negacc, off, 64);
    if (lane == 0) sNeg[wv] = negacc;

    __syncthreads();

    if (t < TILE) {
        atomicAdd(&rowsum[i0 + t], sRow[0][t] + sRow[1][t]);
        if (offdiag)
            atomicAdd(&rowsum[j0 + t], sCol[0][t] + sCol[1][t]);
    }
    if (t == 0)
        negpart[id] = sNeg[0] + sNeg[1] + sNeg[2] + sNeg[3];
}

// ---------------------------------------------------------------------------
// Kernel 3: final scalars. E_i = rowsum[i] (includes +2 from masked entries).
// ---------------------------------------------------------------------------
__global__ __launch_bounds__(1024) void final_kernel(
        const float* __restrict__ rowsum, const float* __restrict__ rnorm,
        const float* __restrict__ posdot, const float* __restrict__ negpart,
        float* __restrict__ out) {
    const int t = threadIdx.x;
    float lsum = 0.f, psum = 0.f, nsum = 0.f;
    #pragma unroll
    for (int i = t; i < NI; i += 1024) {
        const int s = i & (NS - 1);
        const float sp = posdot[s] * rnorm[i] * rnorm[i ^ NS] * TEMP_INV;
        const float E = rowsum[i];
        lsum += logf(expf(sp) + E) - sp;
        psum += sp;
    }
    for (int i = t; i < NTRI; i += 1024)
        nsum += negpart[i];
    __shared__ float red[3][16];
    #pragma unroll
    for (int off = 32; off; off >>= 1) {
        lsum += __shfl_down(lsum, off, 64);
        psum += __shfl_down(psum, off, 64);
        nsum += __shfl_down(nsum, off, 64);
    }
    if ((t & 63) == 0) {
        red[0][t >> 6] = lsum; red[1][t >> 6] = psum; red[2][t >> 6] = nsum;
    }
    __syncthreads();
    if (t == 0) {
        lsum = 0.f; psum = 0.f; nsum = 0.f;
        #pragma unroll
        for (int w = 0; w < 16; ++w) {
            lsum += red[0][w]; psum += red[1][w]; nsum += red[2][w];
        }
        out[0] = lsum / (float)NI;
        out[1] = psum / (float)NI;
        out[2] = nsum / ((float)NI * (float)(NI - 2));
    }
}

// ---------------------------------------------------------------------------
extern "C" void kernel_launch(void* const* d_in, const int* in_sizes, int n_in,
                              void* d_out, int out_size, void* d_ws, size_t ws_size,
                              hipStream_t stream) {
    const float* x1 = (const float*)d_in[0];
    const float* x2 = (const float*)d_in[1];
    float* out = (float*)d_out;

    char* ws = (char*)d_ws;
    __hip_bfloat16* Xb = (__hip_bfloat16*)ws;                 // NI*DIM*2 = 8 MB
    float* rnorm  = (float*)(ws + (size_t)NI * DIM * 2);      // NI
    float* posdot = rnorm + NI;                               // NS
    float* rowsum = posdot + NS;                              // NI (zeroed in prep)
    float* negpart = rowsum + NI;                             // NTRI (all written)

    prep_kernel<<<NS / 2, 256, 0, stream>>>(x1, x2, Xb, rnorm, posdot, rowsum);

    sim_kernel<<<NTRI, 256, 0, stream>>>(Xb, rnorm, rowsum, negpart);

    final_kernel<<<1, 1024, 0, stream>>>(rowsum, rnorm, posdot, negpart, out);
}